// Round 9
// baseline (848.531 us; speedup 1.0000x reference)
//
#include <hip/hip_runtime.h>
#include <hip/hip_cooperative_groups.h>

namespace cg = cooperative_groups;

#define EBLK 1024     // edge kernel threads
#define NPB  98       // nodes owned per edge block
#define TEK  128      // edges per tile (2 x 64-edge sub-tiles)
#define NBLK 512
#define TN   64
#define SB   1024     // sort blocks
#define ST   256      // sort threads  (SB == ST*4 required)

typedef float f32x4 __attribute__((ext_vector_type(4)));
typedef short s16x8 __attribute__((ext_vector_type(8)));

static __device__ __forceinline__ unsigned short f2bf(float f) {
    unsigned int u = __float_as_uint(f);
    u += 0x7FFFu + ((u >> 16) & 1u);          // round-to-nearest-even
    return (unsigned short)(u >> 16);
}
static __device__ __forceinline__ float bf2f(unsigned short s) {
    return __uint_as_float(((unsigned int)s) << 16);
}

// LDS-visibility barrier WITHOUT vmcnt drain (no "memory" clobber).
static __device__ __forceinline__ void bar_sync() {
    __builtin_amdgcn_sched_barrier(0);
    asm volatile("s_waitcnt lgkmcnt(0)");
    __builtin_amdgcn_s_barrier();
    __builtin_amdgcn_sched_barrier(0);
}

// ---------------------------------------------------------------------------
// Fused counting sort (cooperative): hist -> 2-level scan -> scatter keys.
// ---------------------------------------------------------------------------
__global__ __launch_bounds__(ST) void sort_fused(
    const int* __restrict__ ei, int* __restrict__ cur, int* __restrict__ rs,
    int* __restrict__ bsum, uint2* __restrict__ pe_arr, int N, int E)
{
    cg::grid_group grid = cg::this_grid();
    const int gtid = blockIdx.x * ST + threadIdx.x;
    const int gsz  = SB * ST;

    for (int i = gtid; i < N; i += gsz) cur[i] = 0;
    grid.sync();
    for (int e = gtid; e < E; e += gsz) atomicAdd(&cur[ei[E + e]], 1);
    grid.sync();
    // per-block local exclusive scan over its node chunk
    const int chunk = (N + SB - 1) / SB;
    const int nb = blockIdx.x * chunk;
    const int ne = min(nb + chunk, N);
    if (threadIdx.x == 0) {
        int run = 0;
        for (int i = nb; i < ne; ++i) { int c = cur[i]; rs[i] = run; run += c; }
        bsum[blockIdx.x] = run;
    }
    grid.sync();
    // block 0: scan bsum[SB] in parallel (4 per thread + LDS scan)
    if (blockIdx.x == 0) {
        __shared__ int sS[ST];
        int t = threadIdx.x;
        int v0 = bsum[t * 4], v1 = bsum[t * 4 + 1], v2 = bsum[t * 4 + 2], v3 = bsum[t * 4 + 3];
        int tot = v0 + v1 + v2 + v3;
        sS[t] = tot;
        __syncthreads();
        for (int off = 1; off < ST; off <<= 1) {
            int u = (t >= off) ? sS[t - off] : 0;
            __syncthreads();
            sS[t] += u;
            __syncthreads();
        }
        int excl = sS[t] - tot;
        bsum[t * 4]     = excl;
        bsum[t * 4 + 1] = excl + v0;
        bsum[t * 4 + 2] = excl + v0 + v1;
        bsum[t * 4 + 3] = excl + v0 + v1 + v2;
        if (t == ST - 1) rs[N] = excl + tot;
    }
    grid.sync();
    {
        int off = bsum[blockIdx.x];
        if (threadIdx.x == 0)
            for (int i = nb; i < ne; ++i) { rs[i] += off; cur[i] = rs[i]; }
    }
    grid.sync();
    for (int e = gtid; e < E; e += gsz) {
        int d = ei[E + e], s = ei[e];
        int pos = atomicAdd(&cur[d], 1);
        pe_arr[pos] = make_uint2(((unsigned)d << 16) | (unsigned)s, (unsigned)e);
    }
}

// Non-cooperative fallbacks (if cooperative launch is rejected).
__global__ void hist_kernel(const int* __restrict__ ei, int* __restrict__ cnt, int E) {
    int e = blockIdx.x * blockDim.x + threadIdx.x;
    if (e < E) atomicAdd(&cnt[ei[E + e]], 1);
}
__global__ __launch_bounds__(1024) void scan_kernel(int* __restrict__ cur,
                                                    int* __restrict__ rs, int N, int E) {
    __shared__ int s[1024];
    const int tid = threadIdx.x;
    const int chunk = (N + 1023) >> 10;
    const int base = tid * chunk;
    const int end  = min(base + chunk, N);
    int local = 0;
    for (int i = base; i < end; ++i) local += cur[i];
    s[tid] = local;
    __syncthreads();
    for (int off = 1; off < 1024; off <<= 1) {
        int v = (tid >= off) ? s[tid - off] : 0;
        __syncthreads();
        s[tid] += v;
        __syncthreads();
    }
    int run = s[tid] - local;
    for (int i = base; i < end; ++i) {
        int c = cur[i];
        rs[i] = run; cur[i] = run;
        run += c;
    }
    if (tid == 0) rs[N] = E;
}
__global__ void scatter_kernel(const int* __restrict__ ei, int* __restrict__ cur,
                               uint2* __restrict__ pe_arr, int E) {
    int e = blockIdx.x * blockDim.x + threadIdx.x;
    if (e < E) {
        int d = ei[E + e], s = ei[e];
        int pos = atomicAdd(&cur[d], 1);
        pe_arr[pos] = make_uint2(((unsigned)d << 16) | (unsigned)s, (unsigned)e);
    }
}

// ---------------------------------------------------------------------------
// Edge kernel: block owns nodes [b*NPB, b*NPB+NPB), processes its CSR slice in
// consecutive 128-edge tiles. Register segmented-merge -> LDS accum (ds_add),
// plain-store flush. Zero global atomics. LDS ~155.8KB -> 1 block/CU, 16 waves.
// ---------------------------------------------------------------------------
__global__ __launch_bounds__(EBLK) void edge_csr_kernel(
    const float* __restrict__ x,          // [N][96]
    const uint2* __restrict__ pe_arr,     // [E] (dst<<16|src, eid), dst-sorted
    const float* __restrict__ ea,         // [E][17] original order
    const float* __restrict__ W1, const float* __restrict__ b1,
    const float* __restrict__ W2, const float* __restrict__ b2,
    const int* __restrict__ rs,           // [N+1]
    float* agg, int N, int E)
{
    __shared__ unsigned short sBh[9216], sBl[9216];   // W2 hi/lo, fragment-linear
    __shared__ unsigned short sAh[3][TEK][40];        // h hi, chunk-major
    __shared__ unsigned short sAl[3][TEK][40];        // h lo
    __shared__ float sW1[96][20];
    __shared__ float sea[TEK][20];
    __shared__ float accum[NPB][96];
    __shared__ float sb1[96];
    __shared__ int   s_src[TEK], s_dloc[TEK], s_eid[TEK];

    const int tid  = threadIdx.x;
    const int c    = tid & 31;             // h-phase d-lane
    const int g    = (tid >> 5) & 15;      // h-phase 4-edge group within sub
    const int sub  = tid >> 9;             // 0/1
    const int es0  = sub * 64;
    const int lane = tid & 63;
    const int wv8  = (tid >> 6) & 7;
    const int mr   = wv8 & 3;
    const int ng   = wv8 >> 2;
    const int l15  = lane & 15;
    const int l4   = lane >> 4;

    const int nb0    = blockIdx.x * NPB;
    const int ebeg   = rs[min(nb0, N)];
    const int eend   = rs[min(nb0 + NPB, N)];
    const int ecount = eend - ebeg;
    const int ntiles = (ecount + TEK - 1) / TEK;

    // ---- prologue prefetch: ea(tile0) direct, keys(t0), keys(t1) ----
    const int pe = tid >> 3, ps = tid & 7;
    float pf0 = 0.f, pf1 = 0.f, pf2 = 0.f;
    uint2 pk = make_uint2(0u, 0u), pk2 = make_uint2(0u, 0u);
    if (ntiles > 0) {
        int ge = (int)pe_arr[min(ebeg + pe, E - 1)].y;
        const float* er = ea + (size_t)ge * 17;
        pf0 = er[ps];
        pf1 = er[ps + 8];
        if (ps == 0) pf2 = er[16];
        if (tid < TEK) {
            pk  = pe_arr[min(ebeg + tid, E - 1)];
            pk2 = pe_arr[min(ebeg + TEK + tid, E - 1)];
        }
    }

    // ---- one-time staging ----
    for (int idx = tid; idx < 96 * 20; idx += EBLK) {
        int d = idx / 20, k = idx - d * 20;
        sW1[d][k] = (k < 17) ? W1[d * 17 + k] : 0.f;
    }
    for (int idx = tid; idx < 96 * 96; idx += EBLK) {
        int d = idx / 96, k = idx - d * 96;
        float v = W2[idx];
        unsigned short hb = f2bf(v);
        int ngf = d / 48, tt = (d % 48) / 16, r = d & 15;
        int ch = k >> 5, kl4 = (k & 31) >> 3, sb = k & 7;
        int fo = ((((ngf * 3 + tt) * 3 + ch) * 4 + kl4) * 16 + r) * 8 + sb;
        sBh[fo] = hb;
        sBl[fo] = f2bf(v - bf2f(hb));
    }
    if (tid < 96) sb1[tid] = b1[tid];
    if (tid < TEK) { sea[tid][17] = 0.f; sea[tid][18] = 0.f; sea[tid][19] = 0.f; }
    for (int idx = tid; idx < NPB * 96; idx += EBLK) (&accum[0][0])[idx] = 0.f;

    float bias[3]; int dv[3];
    #pragma unroll
    for (int t = 0; t < 3; ++t) {
        dv[t]   = (ng * 3 + t) * 16 + l15;
        bias[t] = b2[dv[t]];
    }

    __syncthreads();   // staging + prologue loads drained
    if (ntiles > 0) {
        sea[pe][ps]     = pf0;
        sea[pe][ps + 8] = pf1;
        if (ps == 0) sea[pe][16] = pf2;
        if (tid < TEK) {
            int e = ebeg + tid;
            s_dloc[tid] = (e < eend) ? (int)(pk.x >> 16) - nb0 : -1;
            s_src[tid]  = (int)(pk.x & 0xFFFFu);
            s_eid[tid]  = (int)pk2.y;
        }
    }
    __syncthreads();

    for (int t = 0; t < ntiles; ++t) {
        const bool nxt = (t + 1) < ntiles;

        // ===== Phase A =====
        const int g16 = es0 + mr * 16;
        int sg[4], dl[4];
        #pragma unroll
        for (int j = 0; j < 4; ++j) {
            int el = g16 + l4 * 4 + j;
            sg[j] = s_src[el];
            dl[j] = s_dloc[el];
        }
        const int dFirst = s_dloc[g16], dLast = s_dloc[g16 + 15];

        // x gathers (oldest VMEM this iteration)
        float xg[12];
        #pragma unroll
        for (int t3 = 0; t3 < 3; ++t3)
            #pragma unroll
            for (int j = 0; j < 4; ++j)
                xg[t3 * 4 + j] = x[(size_t)sg[j] * 96 + dv[t3]];

        // ea-gather(t+1) via s_eid; key loads for (t+1) and (t+2)
        if (nxt) {
            int ge = s_eid[pe];
            const float* er = ea + (size_t)ge * 17;
            pf0 = er[ps];
            pf1 = er[ps + 8];
            if (ps == 0) pf2 = er[16];
            if (tid < TEK) {
                pk  = pe_arr[min(ebeg + (t + 1) * TEK + tid, E - 1)];
                pk2 = pe_arr[min(ebeg + (t + 2) * TEK + tid, E - 1)];
            }
        }

        // h = relu(ea @ W1^T + b1) -> bf16 hi/lo into sA
        {
            float hacc[4][3];
            #pragma unroll
            for (int i = 0; i < 4; ++i) {
                hacc[i][0] = sb1[c]; hacc[i][1] = sb1[c + 32]; hacc[i][2] = sb1[c + 64];
            }
            #pragma unroll
            for (int k0 = 0; k0 < 20; k0 += 4) {
                float4 w0 = *(const float4*)&sW1[c][k0];
                float4 w1 = *(const float4*)&sW1[c + 32][k0];
                float4 w2 = *(const float4*)&sW1[c + 64][k0];
                #pragma unroll
                for (int i = 0; i < 4; ++i) {
                    float4 av = *(const float4*)&sea[es0 + g * 4 + i][k0];
                    hacc[i][0] = fmaf(av.w, w0.w, fmaf(av.z, w0.z, fmaf(av.y, w0.y, fmaf(av.x, w0.x, hacc[i][0]))));
                    hacc[i][1] = fmaf(av.w, w1.w, fmaf(av.z, w1.z, fmaf(av.y, w1.y, fmaf(av.x, w1.x, hacc[i][1]))));
                    hacc[i][2] = fmaf(av.w, w2.w, fmaf(av.z, w2.z, fmaf(av.y, w2.y, fmaf(av.x, w2.x, hacc[i][2]))));
                }
            }
            #pragma unroll
            for (int i = 0; i < 4; ++i) {
                int e = es0 + g * 4 + i;
                #pragma unroll
                for (int j = 0; j < 3; ++j) {
                    float v = fmaxf(hacc[i][j], 0.f);
                    unsigned short hb = f2bf(v);
                    sAh[j][e][c] = hb;
                    sAl[j][e][c] = f2bf(v - bf2f(hb));
                }
            }
        }
        bar_sync();   // BAR1: sA visible; VMEM rides

        // ===== Phase B =====
        f32x4 acc[3];
        #pragma unroll
        for (int t3 = 0; t3 < 3; ++t3) acc[t3] = (f32x4){0.f, 0.f, 0.f, 0.f};
        const int arow = es0 + mr * 16 + l15;
        #pragma unroll
        for (int chunk = 0; chunk < 3; ++chunk) {
            s16x8 a_hi = *(const s16x8*)&sAh[chunk][arow][l4 * 8];
            s16x8 a_lo = *(const s16x8*)&sAl[chunk][arow][l4 * 8];
            #pragma unroll
            for (int t3 = 0; t3 < 3; ++t3) {
                const int base = (((ng * 3 + t3) * 3 + chunk) * 64 + lane) * 8;
                s16x8 b_hi = *(const s16x8*)&sBh[base];
                s16x8 b_lo = *(const s16x8*)&sBl[base];
                acc[t3] = __builtin_amdgcn_mfma_f32_16x16x32_bf16(a_hi, b_hi, acc[t3], 0, 0, 0);
                acc[t3] = __builtin_amdgcn_mfma_f32_16x16x32_bf16(a_hi, b_lo, acc[t3], 0, 0, 0);
                acc[t3] = __builtin_amdgcn_mfma_f32_16x16x32_bf16(a_lo, b_hi, acc[t3], 0, 0, 0);
            }
        }

        // stage tile t+1 (counted vmcnt: ea-pf then keys are newest; no atomics in queue)
        if (nxt) {
            sea[pe][ps]     = pf0;
            sea[pe][ps + 8] = pf1;
            if (ps == 0) sea[pe][16] = pf2;
            if (tid < TEK) {
                int e = ebeg + (t + 1) * TEK + tid;
                s_dloc[tid] = (e < eend) ? (int)(pk.x >> 16) - nb0 : -1;
                s_src[tid]  = (int)(pk.x & 0xFFFFu);
                s_eid[tid]  = (int)pk2.y;
            }
        }

        // messages + register segmented merge -> LDS accum (ds_add)
        float v[3][4];
        #pragma unroll
        for (int t3 = 0; t3 < 3; ++t3)
            #pragma unroll
            for (int j = 0; j < 4; ++j)
                v[t3][j] = (acc[t3][j] + bias[t3]) * xg[t3 * 4 + j];

        if (dFirst == dLast) {
            if (dFirst >= 0) {
                #pragma unroll
                for (int t3 = 0; t3 < 3; ++t3) {
                    float s4 = (v[t3][0] + v[t3][1]) + (v[t3][2] + v[t3][3]);
                    s4 += __shfl_xor(s4, 16, 64);
                    s4 += __shfl_xor(s4, 32, 64);
                    if (l4 == 0)
                        atomicAdd(&accum[dFirst][dv[t3]], s4);
                }
            }
        } else {
            #pragma unroll
            for (int t3 = 0; t3 < 3; ++t3) {
                float a = v[t3][0]; int cd = dl[0];
                #pragma unroll
                for (int j = 1; j < 4; ++j) {
                    if (dl[j] == cd) a += v[t3][j];
                    else {
                        if (cd >= 0) atomicAdd(&accum[cd][dv[t3]], a);
                        a = v[t3][j]; cd = dl[j];
                    }
                }
                if (cd >= 0) atomicAdd(&accum[cd][dv[t3]], a);
            }
        }

        bar_sync();   // BAR2
    }

    __syncthreads();
    // flush owned node range: plain coalesced stores, full coverage
    for (int idx = tid; idx < NPB * 96; idx += EBLK) {
        int n = nb0 + idx / 96;
        if (n < N) agg[(size_t)n * 96 + (idx % 96)] = (&accum[0][0])[idx];
    }
}

// ---------------------------------------------------------------------------
// Fallback edge kernel (proven atomic version): used only if ws too small.
// ---------------------------------------------------------------------------
__global__ __launch_bounds__(512, 4) void edge_kernel_atomic(
    const float* __restrict__ x, const int* __restrict__ ei,
    const float* __restrict__ ea, const float* __restrict__ W1,
    const float* __restrict__ b1, const float* __restrict__ W2,
    const float* __restrict__ b2, float* __restrict__ agg, int N, int E)
{
    __shared__ unsigned short sBh[9216], sBl[9216];
    __shared__ unsigned short sAh[3][64][40], sAl[3][64][40];
    __shared__ float sW1[96][20];
    __shared__ float sea[64][20];
    __shared__ float sb1[96];
    __shared__ int   ssrc[64], sdst[64];

    const int tid = threadIdx.x;
    const int c = tid & 31, g = tid >> 5;
    const int lane = tid & 63, wv = tid >> 6;
    const int mr = wv & 3, ng = wv >> 2;
    const int l15 = lane & 15, l4 = lane >> 4;
    const int ntiles = (E + 63) / 64;

    for (int idx = tid; idx < 96 * 20; idx += 512) {
        int d = idx / 20, k = idx - d * 20;
        sW1[d][k] = (k < 17) ? W1[d * 17 + k] : 0.f;
    }
    for (int idx = tid; idx < 96 * 96; idx += 512) {
        int d = idx / 96, k = idx - d * 96;
        float v = W2[idx];
        unsigned short hb = f2bf(v);
        int ngf = d / 48, tt = (d % 48) / 16, r = d & 15;
        int ch = k >> 5, kl4 = (k & 31) >> 3, sb = k & 7;
        int fo = ((((ngf * 3 + tt) * 3 + ch) * 4 + kl4) * 16 + r) * 8 + sb;
        sBh[fo] = hb; sBl[fo] = f2bf(v - bf2f(hb));
    }
    if (tid < 96) sb1[tid] = b1[tid];
    float bias[3]; int dv[3];
    #pragma unroll
    for (int t = 0; t < 3; ++t) { dv[t] = (ng * 3 + t) * 16 + l15; bias[t] = b2[dv[t]]; }

    for (int tile = blockIdx.x; tile < ntiles; tile += 512) {
        const int e0 = tile * 64;
        __syncthreads();
        for (int idx = tid; idx < 64 * 20; idx += 512) {
            int e = idx / 20, k = idx - e * 20;
            float v = 0.f;
            if (k < 17 && e0 + e < E) v = ea[(size_t)(e0 + e) * 17 + k];
            sea[e][k] = v;
        }
        if (tid < 64) {
            int e = e0 + tid;
            ssrc[tid] = (e < E) ? ei[e] : 0;
            sdst[tid] = (e < E) ? ei[E + e] : 0;
        }
        __syncthreads();
        {
            float hacc[4][3];
            #pragma unroll
            for (int i = 0; i < 4; ++i) { hacc[i][0]=sb1[c]; hacc[i][1]=sb1[c+32]; hacc[i][2]=sb1[c+64]; }
            #pragma unroll
            for (int k0 = 0; k0 < 20; k0 += 4) {
                float4 w0 = *(const float4*)&sW1[c][k0];
                float4 w1 = *(const float4*)&sW1[c + 32][k0];
                float4 w2 = *(const float4*)&sW1[c + 64][k0];
                #pragma unroll
                for (int i = 0; i < 4; ++i) {
                    float4 av = *(const float4*)&sea[g * 4 + i][k0];
                    hacc[i][0] = fmaf(av.w, w0.w, fmaf(av.z, w0.z, fmaf(av.y, w0.y, fmaf(av.x, w0.x, hacc[i][0]))));
                    hacc[i][1] = fmaf(av.w, w1.w, fmaf(av.z, w1.z, fmaf(av.y, w1.y, fmaf(av.x, w1.x, hacc[i][1]))));
                    hacc[i][2] = fmaf(av.w, w2.w, fmaf(av.z, w2.z, fmaf(av.y, w2.y, fmaf(av.x, w2.x, hacc[i][2]))));
                }
            }
            #pragma unroll
            for (int i = 0; i < 4; ++i) {
                int e = g * 4 + i;
                #pragma unroll
                for (int j = 0; j < 3; ++j) {
                    float v = fmaxf(hacc[i][j], 0.f);
                    unsigned short hb = f2bf(v);
                    sAh[j][e][c] = hb; sAl[j][e][c] = f2bf(v - bf2f(hb));
                }
            }
        }
        __syncthreads();
        f32x4 acc[3];
        #pragma unroll
        for (int t = 0; t < 3; ++t) acc[t] = (f32x4){0.f, 0.f, 0.f, 0.f};
        const int arow = mr * 16 + l15;
        #pragma unroll
        for (int chunk = 0; chunk < 3; ++chunk) {
            s16x8 a_hi = *(const s16x8*)&sAh[chunk][arow][l4 * 8];
            s16x8 a_lo = *(const s16x8*)&sAl[chunk][arow][l4 * 8];
            #pragma unroll
            for (int t = 0; t < 3; ++t) {
                const int base = (((ng * 3 + t) * 3 + chunk) * 64 + lane) * 8;
                s16x8 b_hi = *(const s16x8*)&sBh[base];
                s16x8 b_lo = *(const s16x8*)&sBl[base];
                acc[t] = __builtin_amdgcn_mfma_f32_16x16x32_bf16(a_hi, b_hi, acc[t], 0, 0, 0);
                acc[t] = __builtin_amdgcn_mfma_f32_16x16x32_bf16(a_hi, b_lo, acc[t], 0, 0, 0);
                acc[t] = __builtin_amdgcn_mfma_f32_16x16x32_bf16(a_lo, b_hi, acc[t], 0, 0, 0);
            }
        }
        #pragma unroll
        for (int t = 0; t < 3; ++t)
            #pragma unroll
            for (int j = 0; j < 4; ++j) {
                int el = mr * 16 + l4 * 4 + j;
                int e  = e0 + el;
                if (e < E) {
                    int s = ssrc[el], dn = sdst[el];
                    atomicAdd(&agg[(size_t)dn * 96 + dv[t]],
                              (acc[t][j] + bias[t]) * x[(size_t)s * 96 + dv[t]]);
                }
            }
    }
}

// ---------------------------------------------------------------------------
// Node kernel: out = relu(x @ Ws^T + bs + agg @ Wn^T + bn); agg may alias out.
// ---------------------------------------------------------------------------
__global__ __launch_bounds__(NBLK, 4) void node_kernel(
    const float* __restrict__ x,
    const float* agg,
    const float* __restrict__ Ws, const float* __restrict__ bs,
    const float* __restrict__ Wn, const float* __restrict__ bn,
    float* out, int N)
{
    __shared__ float sW[96][100];
    __shared__ float sxa[TN][100];
    __shared__ float sbias[96];

    const int tid = threadIdx.x;
    const int c = tid & 31, g = tid >> 5;
    const int n0 = blockIdx.x * TN;

    if (tid < 96) sbias[tid] = bs[tid] + bn[tid];

    float acc[4][3];
    #pragma unroll
    for (int i = 0; i < 4; ++i)
        for (int j = 0; j < 3; ++j) acc[i][j] = 0.f;

    for (int ph = 0; ph < 2; ++ph) {
        const float* W   = ph ? Wn : Ws;
        const float* src = ph ? agg : x;
        __syncthreads();
        for (int idx = tid; idx < 96 * 24; idx += NBLK) {
            int d = idx / 24, kq = idx - d * 24;
            *(float4*)&sW[d][kq * 4] = *(const float4*)&W[d * 96 + kq * 4];
        }
        for (int idx = tid; idx < TN * 24; idx += NBLK) {
            int n = idx / 24, kq = idx - n * 24;
            float4 v = make_float4(0.f, 0.f, 0.f, 0.f);
            if (n0 + n < N) v = *(const float4*)&src[(size_t)(n0 + n) * 96 + kq * 4];
            *(float4*)&sxa[n][kq * 4] = v;
        }
        __syncthreads();
        #pragma unroll 2
        for (int k0 = 0; k0 < 96; k0 += 4) {
            float4 w0 = *(const float4*)&sW[c][k0];
            float4 w1 = *(const float4*)&sW[c + 32][k0];
            float4 w2 = *(const float4*)&sW[c + 64][k0];
            #pragma unroll
            for (int i = 0; i < 4; ++i) {
                float4 xv = *(const float4*)&sxa[g * 4 + i][k0];
                acc[i][0] = fmaf(xv.w, w0.w, fmaf(xv.z, w0.z, fmaf(xv.y, w0.y, fmaf(xv.x, w0.x, acc[i][0]))));
                acc[i][1] = fmaf(xv.w, w1.w, fmaf(xv.z, w1.z, fmaf(xv.y, w1.y, fmaf(xv.x, w1.x, acc[i][1]))));
                acc[i][2] = fmaf(xv.w, w2.w, fmaf(xv.z, w2.z, fmaf(xv.y, w2.y, fmaf(xv.x, w2.x, acc[i][2]))));
            }
        }
    }

    #pragma unroll
    for (int i = 0; i < 4; ++i) {
        int n = n0 + g * 4 + i;
        if (n < N) {
            out[(size_t)n * 96 + c]      = fmaxf(acc[i][0] + sbias[c], 0.f);
            out[(size_t)n * 96 + c + 32] = fmaxf(acc[i][1] + sbias[c + 32], 0.f);
            out[(size_t)n * 96 + c + 64] = fmaxf(acc[i][2] + sbias[c + 64], 0.f);
        }
    }
}

extern "C" void kernel_launch(void* const* d_in, const int* in_sizes, int n_in,
                              void* d_out, int out_size, void* d_ws, size_t ws_size,
                              hipStream_t stream) {
    const float* x  = (const float*)d_in[0];
    const int*   ei = (const int*)d_in[1];
    const float* ea = (const float*)d_in[2];
    const float* W1 = (const float*)d_in[3];
    const float* b1 = (const float*)d_in[4];
    const float* W2 = (const float*)d_in[5];
    const float* b2 = (const float*)d_in[6];
    const float* Ws = (const float*)d_in[7];
    const float* bs = (const float*)d_in[8];
    const float* Wn = (const float*)d_in[9];
    const float* bn = (const float*)d_in[10];
    float* out = (float*)d_out;

    const int N = in_sizes[0] / 96;
    const int E = in_sizes[2] / 17;

    // ws: pe_arr[E] (8B) | cur[N] | rs[N+1] | bsum[SB]
    const size_t need = (size_t)E * 8 + ((size_t)2 * N + 1 + SB) * 4;

    if (ws_size >= need) {
        uint2* pe_arr = (uint2*)d_ws;
        int*   cur    = (int*)(pe_arr + E);
        int*   rs     = cur + N;
        int*   bsum   = rs + N + 1;

        void* args[] = {(void*)&ei, (void*)&cur, (void*)&rs, (void*)&bsum,
                        (void*)&pe_arr, (void*)&N, (void*)&E};
        hipError_t cerr = hipLaunchCooperativeKernel((const void*)sort_fused,
                                                     dim3(SB), dim3(ST), args, 0, stream);
        if (cerr != hipSuccess) {
            // fallback: separate sort dispatches
            hipMemsetAsync(cur, 0, (size_t)N * sizeof(int), stream);
            hist_kernel<<<(E + 255) / 256, 256, 0, stream>>>(ei, cur, E);
            scan_kernel<<<1, 1024, 0, stream>>>(cur, rs, N, E);
            scatter_kernel<<<(E + 255) / 256, 256, 0, stream>>>(ei, cur, pe_arr, E);
        }
        // agg = out; edge_csr writes every row (no memset needed)
        edge_csr_kernel<<<(N + NPB - 1) / NPB, EBLK, 0, stream>>>(
            x, pe_arr, ea, W1, b1, W2, b2, rs, out, N, E);
    } else {
        hipMemsetAsync(out, 0, (size_t)N * 96 * sizeof(float), stream);
        edge_kernel_atomic<<<512, 512, 0, stream>>>(x, ei, ea, W1, b1, W2, b2, out, N, E);
    }
    node_kernel<<<(N + TN - 1) / TN, NBLK, 0, stream>>>(x, out, Ws, bs, Wn, bn, out, N);
}

// Round 11
// 618.818 us; speedup vs baseline: 1.3712x; 1.3712x over previous
//
#include <hip/hip_runtime.h>

#define EBLK 1024     // edge kernel threads (16 waves)
#define NPB  104      // nodes owned per edge block
#define TEK  128      // edges per tile
#define NBLK 512
#define TN   64
#define LBK  544      // padded bucket capacity (>= nb)

typedef float f32x4 __attribute__((ext_vector_type(4)));
typedef short s16x8 __attribute__((ext_vector_type(8)));
typedef unsigned long long u64;

static __device__ __forceinline__ unsigned short f2bf(float f) {
    unsigned int u = __float_as_uint(f);
    u += 0x7FFFu + ((u >> 16) & 1u);          // round-to-nearest-even
    return (unsigned short)(u >> 16);
}
static __device__ __forceinline__ float bf2f(unsigned short s) {
    return __uint_as_float(((unsigned int)s) << 16);
}
static __device__ __forceinline__ u64 pack4(unsigned short a, unsigned short b,
                                            unsigned short c, unsigned short d) {
    return (u64)a | ((u64)b << 16) | ((u64)c << 32) | ((u64)d << 48);
}

// LDS-visibility barrier WITHOUT vmcnt drain (no "memory" clobber).
static __device__ __forceinline__ void bar_sync() {
    __builtin_amdgcn_sched_barrier(0);
    asm volatile("s_waitcnt lgkmcnt(0)");
    __builtin_amdgcn_s_barrier();
    __builtin_amdgcn_sched_barrier(0);
}

// ---------------------------------------------------------------------------
// Bucket sort (by dst/NPB). cntpad is stride-16 padded (1 counter / 64B line).
// ---------------------------------------------------------------------------
__global__ __launch_bounds__(256) void hist_bucket(const int* __restrict__ ei,
                                                   int* __restrict__ cntpad, int E, int nb) {
    __shared__ int lh[LBK];
    for (int i = threadIdx.x; i < LBK; i += 256) lh[i] = 0;
    __syncthreads();
    for (int e = blockIdx.x * 256 + threadIdx.x; e < E; e += gridDim.x * 256)
        atomicAdd(&lh[ei[E + e] / NPB], 1);
    __syncthreads();
    for (int i = threadIdx.x; i < nb; i += 256)
        if (lh[i]) atomicAdd(&cntpad[i * 16], lh[i]);
}

__global__ __launch_bounds__(1024) void scan_bucket(int* __restrict__ cntpad,
                                                    int* __restrict__ rs, int nb) {
    __shared__ int s[1024];
    int t = threadIdx.x;
    int v = (t < nb) ? cntpad[t * 16] : 0;
    s[t] = v;
    __syncthreads();
    for (int off = 1; off < 1024; off <<= 1) {
        int u = (t >= off) ? s[t - off] : 0;
        __syncthreads();
        s[t] += u;
        __syncthreads();
    }
    int excl = s[t] - v;
    if (t < nb) { rs[t] = excl; cntpad[t * 16] = excl; }
    if (t == nb - 1) rs[nb] = excl + v;
}

__global__ __launch_bounds__(256) void scatter_bucket(const int* __restrict__ ei,
                                                      int* __restrict__ cntpad,
                                                      uint2* __restrict__ pe_arr, int E) {
    int e = blockIdx.x * 256 + threadIdx.x;
    if (e < E) {
        int d = ei[E + e], s0 = ei[e];
        int pos = atomicAdd(&cntpad[(d / NPB) * 16], 1);
        pe_arr[pos] = make_uint2(((unsigned)d << 16) | (unsigned)s0, (unsigned)e);
    }
}

// swizzled byte offsets: 64B rows, XOR 16B chunk by (edge&3)
#define SEA_BYTE(edge, kbyte) ((((edge)*64) + (kbyte)) ^ (((edge)&3) << 4))
#define SA_BYTE(ch, edge, kbyte) (((((ch)*TEK + (edge)) * 64) + (kbyte)) ^ (((edge)&3) << 4))

// ---------------------------------------------------------------------------
// Edge kernel: block owns nodes [b*NPB,(b+1)*NPB), bucket-sorted edge slice.
//  A: gathers x(t) | ea-gather(t+1) via s_eid | keys(t+1),(t+2) |
//     GEMM1 (MFMA): h = relu(ea@W1^T+b1), A=W1 so D rows are dv -> b64 writes
//  BAR (lgkm only)
//  B: GEMM2 (MFMA split-3) | stage sea/keys(t+1) | merge -> ds_add accum
//  BAR (lgkm only)
// Flush: plain stores. Zero global atomics. LDS ~152.5KB.
// NOTE: buckets are NOT sorted within -> uniformity needs __all over the wave
// (r10 bug: endpoint check was only valid for fully-sorted input).
// ---------------------------------------------------------------------------
__global__ __launch_bounds__(EBLK) void edge_csr_kernel(
    const float* __restrict__ x,          // [N][96]
    const uint2* __restrict__ pe_arr,     // [E] (dst<<16|src, eid), bucket-sorted
    const float* __restrict__ ea,         // [E][17] original order
    const float* __restrict__ W1, const float* __restrict__ b1,
    const float* __restrict__ W2, const float* __restrict__ b2,
    const int* __restrict__ rs,           // [nb+1] bucket starts
    float* agg, int N, int E)
{
    __shared__ unsigned short sBh[9216], sBl[9216];       // W2 hi/lo fragment-linear
    __shared__ unsigned short sAh[3 * TEK * 32];          // h hi, swizzled 64B rows
    __shared__ unsigned short sAl[3 * TEK * 32];          // h lo
    __shared__ unsigned short sW1h[3072], sW1l[3072];     // W1 hi/lo fragment-linear (K=32)
    __shared__ unsigned short seaH[TEK * 32], seaL[TEK * 32]; // ea bf16, swizzled
    __shared__ float accum[NPB][96];
    __shared__ int s_src[TEK], s_dloc[TEK], s_eid[TEK];

    const int tid  = threadIdx.x;
    const int sub  = tid >> 9;             // 0/1 (GEMM2 sub-tile)
    const int es0  = sub * 64;
    const int lane = tid & 63;
    const int wv8  = (tid >> 6) & 7;
    const int mr   = wv8 & 3;
    const int ng   = wv8 >> 2;
    const int l15  = lane & 15;
    const int l4   = lane >> 4;
    const int w    = tid >> 6;             // wave 0..15 (GEMM1)
    const int nt   = w & 7;                // GEMM1 n-tile (16 edges)
    const int mg   = (w >> 3) * 3;         // GEMM1 m-tile group (3 tiles of 16 dv)
    const int eb   = nt * 16 + l15;        // GEMM1 edge column

    const int nb0    = blockIdx.x * NPB;
    const int ebeg   = rs[blockIdx.x];
    const int eend   = rs[blockIdx.x + 1];
    const int ecount = eend - ebeg;
    const int ntiles = (ecount + TEK - 1) / TEK;

    // ---- prologue prefetch: ea(tile0) direct, keys(t0), keys(t1) ----
    const int pe = tid >> 3, ps = tid & 7;
    float pf0 = 0.f, pf1 = 0.f, pf2 = 0.f;
    uint2 pk = make_uint2(0u, 0u), pk2 = make_uint2(0u, 0u);
    if (ntiles > 0) {
        int ge = (int)pe_arr[min(ebeg + pe, E - 1)].y;
        const float* er = ea + (size_t)ge * 17;
        pf0 = er[ps];
        pf1 = er[ps + 8];
        if (ps == 0) pf2 = er[16];
        if (tid < TEK) {
            pk  = pe_arr[min(ebeg + tid, E - 1)];
            pk2 = pe_arr[min(ebeg + TEK + tid, E - 1)];
        }
    }

    // ---- one-time staging ----
    for (int idx = tid; idx < 96 * 96; idx += EBLK) {
        int d = idx / 96, k = idx - d * 96;
        float v = W2[idx];
        unsigned short hb = f2bf(v);
        int ngf = d / 48, tt = (d % 48) / 16, r = d & 15;
        int ch = k >> 5, kl4 = (k & 31) >> 3, sb = k & 7;
        int fo = ((((ngf * 3 + tt) * 3 + ch) * 4 + kl4) * 16 + r) * 8 + sb;
        sBh[fo] = hb;
        sBl[fo] = f2bf(v - bf2f(hb));
    }
    for (int idx = tid; idx < 96 * 32; idx += EBLK) {
        int d = idx >> 5, k = idx & 31;
        float v = (k < 17) ? W1[d * 17 + k] : 0.f;
        unsigned short hb = f2bf(v);
        int mt = d >> 4, r = d & 15;
        int fo = ((mt * 4 + (k >> 3)) * 16 + r) * 8 + (k & 7);
        sW1h[fo] = hb;
        sW1l[fo] = f2bf(v - bf2f(hb));
    }
    for (int idx = tid; idx < TEK * 32; idx += EBLK) { seaH[idx] = 0; seaL[idx] = 0; }
    for (int idx = tid; idx < NPB * 96; idx += EBLK) (&accum[0][0])[idx] = 0.f;

    float b1v[3][4];
    #pragma unroll
    for (int i = 0; i < 3; ++i)
        #pragma unroll
        for (int j = 0; j < 4; ++j)
            b1v[i][j] = b1[(mg + i) * 16 + l4 * 4 + j];

    float bias[3]; int dv[3];
    #pragma unroll
    for (int t = 0; t < 3; ++t) {
        dv[t]   = (ng * 3 + t) * 16 + l15;
        bias[t] = b2[dv[t]];
    }

    __syncthreads();   // staging + prologue loads drained (once)
    if (ntiles > 0) {
        {   // stage tile0 ea as bf16 hi/lo (swizzled)
            unsigned short hb = f2bf(pf0);
            *(unsigned short*)((char*)seaH + SEA_BYTE(pe, ps * 2)) = hb;
            *(unsigned short*)((char*)seaL + SEA_BYTE(pe, ps * 2)) = f2bf(pf0 - bf2f(hb));
            hb = f2bf(pf1);
            *(unsigned short*)((char*)seaH + SEA_BYTE(pe, (ps + 8) * 2)) = hb;
            *(unsigned short*)((char*)seaL + SEA_BYTE(pe, (ps + 8) * 2)) = f2bf(pf1 - bf2f(hb));
            if (ps == 0) {
                hb = f2bf(pf2);
                *(unsigned short*)((char*)seaH + SEA_BYTE(pe, 32)) = hb;
                *(unsigned short*)((char*)seaL + SEA_BYTE(pe, 32)) = f2bf(pf2 - bf2f(hb));
            }
        }
        if (tid < TEK) {
            int e = ebeg + tid;
            s_dloc[tid] = (e < eend) ? (int)(pk.x >> 16) - nb0 : -1;
            s_src[tid]  = (int)(pk.x & 0xFFFFu);
            s_eid[tid]  = (int)pk2.y;
        }
    }
    __syncthreads();

    for (int t = 0; t < ntiles; ++t) {
        const bool nxt = (t + 1) < ntiles;

        // ===== Phase A =====
        const int g16 = es0 + mr * 16;
        int sg[4], dl[4];
        #pragma unroll
        for (int j = 0; j < 4; ++j) {
            int el = g16 + l4 * 4 + j;
            sg[j] = s_src[el];
            dl[j] = s_dloc[el];
        }
        const int dFirst = s_dloc[g16];

        // x gathers (oldest VMEM)
        float xg[12];
        #pragma unroll
        for (int t3 = 0; t3 < 3; ++t3)
            #pragma unroll
            for (int j = 0; j < 4; ++j)
                xg[t3 * 4 + j] = x[(size_t)sg[j] * 96 + dv[t3]];

        // ea-gather(t+1) via s_eid; key loads (t+1),(t+2)
        if (nxt) {
            int ge = s_eid[pe];
            const float* er = ea + (size_t)ge * 17;
            pf0 = er[ps];
            pf1 = er[ps + 8];
            if (ps == 0) pf2 = er[16];
            if (tid < TEK) {
                pk  = pe_arr[min(ebeg + (t + 1) * TEK + tid, E - 1)];
                pk2 = pe_arr[min(ebeg + (t + 2) * TEK + tid, E - 1)];
            }
        }

        // GEMM1: h = relu(ea @ W1^T + b1) via MFMA (A=W1 -> D rows = dv)
        {
            s16x8 bh = *(const s16x8*)((const char*)seaH + SEA_BYTE(eb, l4 * 16));
            s16x8 bl = *(const s16x8*)((const char*)seaL + SEA_BYTE(eb, l4 * 16));
            #pragma unroll
            for (int i = 0; i < 3; ++i) {
                const int mt = mg + i;
                s16x8 ah = *(const s16x8*)&sW1h[((mt * 4 + l4) * 16 + l15) * 8];
                s16x8 al = *(const s16x8*)&sW1l[((mt * 4 + l4) * 16 + l15) * 8];
                f32x4 dd = (f32x4){0.f, 0.f, 0.f, 0.f};
                dd = __builtin_amdgcn_mfma_f32_16x16x32_bf16(ah, bh, dd, 0, 0, 0);
                dd = __builtin_amdgcn_mfma_f32_16x16x32_bf16(al, bh, dd, 0, 0, 0);
                dd = __builtin_amdgcn_mfma_f32_16x16x32_bf16(ah, bl, dd, 0, 0, 0);
                unsigned short hh[4], hl[4];
                #pragma unroll
                for (int j = 0; j < 4; ++j) {
                    float hv = fmaxf(dd[j] + b1v[i][j], 0.f);
                    hh[j] = f2bf(hv);
                    hl[j] = f2bf(hv - bf2f(hh[j]));
                }
                const int db = mt * 16 + l4 * 4;
                const int by = SA_BYTE(db >> 5, eb, (db & 31) * 2);
                *(u64*)((char*)sAh + by) = pack4(hh[0], hh[1], hh[2], hh[3]);
                *(u64*)((char*)sAl + by) = pack4(hl[0], hl[1], hl[2], hl[3]);
            }
        }
        bar_sync();   // BAR1: sA visible; VMEM rides

        // ===== Phase B =====
        f32x4 acc[3];
        #pragma unroll
        for (int t3 = 0; t3 < 3; ++t3) acc[t3] = (f32x4){0.f, 0.f, 0.f, 0.f};
        const int arow = es0 + mr * 16 + l15;
        #pragma unroll
        for (int chunk = 0; chunk < 3; ++chunk) {
            s16x8 a_hi = *(const s16x8*)((const char*)sAh + SA_BYTE(chunk, arow, l4 * 16));
            s16x8 a_lo = *(const s16x8*)((const char*)sAl + SA_BYTE(chunk, arow, l4 * 16));
            #pragma unroll
            for (int t3 = 0; t3 < 3; ++t3) {
                const int base = (((ng * 3 + t3) * 3 + chunk) * 64 + lane) * 8;
                s16x8 b_hi = *(const s16x8*)&sBh[base];
                s16x8 b_lo = *(const s16x8*)&sBl[base];
                acc[t3] = __builtin_amdgcn_mfma_f32_16x16x32_bf16(a_hi, b_hi, acc[t3], 0, 0, 0);
                acc[t3] = __builtin_amdgcn_mfma_f32_16x16x32_bf16(a_hi, b_lo, acc[t3], 0, 0, 0);
                acc[t3] = __builtin_amdgcn_mfma_f32_16x16x32_bf16(a_lo, b_hi, acc[t3], 0, 0, 0);
            }
        }

        // stage tile t+1 (counted vmcnt waits the prefetch/gathers)
        if (nxt) {
            unsigned short hb = f2bf(pf0);
            *(unsigned short*)((char*)seaH + SEA_BYTE(pe, ps * 2)) = hb;
            *(unsigned short*)((char*)seaL + SEA_BYTE(pe, ps * 2)) = f2bf(pf0 - bf2f(hb));
            hb = f2bf(pf1);
            *(unsigned short*)((char*)seaH + SEA_BYTE(pe, (ps + 8) * 2)) = hb;
            *(unsigned short*)((char*)seaL + SEA_BYTE(pe, (ps + 8) * 2)) = f2bf(pf1 - bf2f(hb));
            if (ps == 0) {
                hb = f2bf(pf2);
                *(unsigned short*)((char*)seaH + SEA_BYTE(pe, 32)) = hb;
                *(unsigned short*)((char*)seaL + SEA_BYTE(pe, 32)) = f2bf(pf2 - bf2f(hb));
            }
            if (tid < TEK) {
                int e = ebeg + (t + 1) * TEK + tid;
                s_dloc[tid] = (e < eend) ? (int)(pk.x >> 16) - nb0 : -1;
                s_src[tid]  = (int)(pk.x & 0xFFFFu);
                s_eid[tid]  = (int)pk2.y;
            }
        }

        // messages + register merge -> LDS accum
        float v[3][4];
        #pragma unroll
        for (int t3 = 0; t3 < 3; ++t3)
            #pragma unroll
            for (int j = 0; j < 4; ++j)
                v[t3][j] = (acc[t3][j] + bias[t3]) * xg[t3 * 4 + j];

        // TRUE uniformity: all 16 edges of the group equal (wave-wide __all).
        bool myuni = (dl[0] == dFirst) & (dl[1] == dFirst) &
                     (dl[2] == dFirst) & (dl[3] == dFirst);
        if (__all(myuni) && dFirst >= 0) {
            #pragma unroll
            for (int t3 = 0; t3 < 3; ++t3) {
                float s4 = (v[t3][0] + v[t3][1]) + (v[t3][2] + v[t3][3]);
                s4 += __shfl_xor(s4, 16, 64);
                s4 += __shfl_xor(s4, 32, 64);
                if (l4 == 0)
                    atomicAdd(&accum[dFirst][dv[t3]], s4);
            }
        } else {
            #pragma unroll
            for (int t3 = 0; t3 < 3; ++t3) {
                float a = v[t3][0]; int cd = dl[0];
                #pragma unroll
                for (int j = 1; j < 4; ++j) {
                    if (dl[j] == cd) a += v[t3][j];
                    else {
                        if (cd >= 0) atomicAdd(&accum[cd][dv[t3]], a);
                        a = v[t3][j]; cd = dl[j];
                    }
                }
                if (cd >= 0) atomicAdd(&accum[cd][dv[t3]], a);
            }
        }

        bar_sync();   // BAR2
    }

    __syncthreads();
    for (int idx = tid; idx < NPB * 96; idx += EBLK) {
        int n = nb0 + idx / 96;
        if (n < N) agg[(size_t)n * 96 + (idx % 96)] = (&accum[0][0])[idx];
    }
}

// ---------------------------------------------------------------------------
// Fallback edge kernel (proven r4 atomic version): used only if ws too small.
// ---------------------------------------------------------------------------
__global__ __launch_bounds__(512, 4) void edge_kernel_atomic(
    const float* __restrict__ x, const int* __restrict__ ei,
    const float* __restrict__ ea, const float* __restrict__ W1,
    const float* __restrict__ b1, const float* __restrict__ W2,
    const float* __restrict__ b2, float* __restrict__ agg, int N, int E)
{
    __shared__ unsigned short sBh[9216], sBl[9216];
    __shared__ unsigned short sAh2[3][64][40], sAl2[3][64][40];
    __shared__ float sW1f[96][20];
    __shared__ float sea[64][20];
    __shared__ float sb1[96];
    __shared__ int   ssrc[64], sdst[64];

    const int tid = threadIdx.x;
    const int c = tid & 31, g = tid >> 5;
    const int lane = tid & 63, wv = tid >> 6;
    const int mr = wv & 3, ng = wv >> 2;
    const int l15 = lane & 15, l4 = lane >> 4;
    const int ntiles = (E + 63) / 64;

    for (int idx = tid; idx < 96 * 20; idx += 512) {
        int d = idx / 20, k = idx - d * 20;
        sW1f[d][k] = (k < 17) ? W1[d * 17 + k] : 0.f;
    }
    for (int idx = tid; idx < 96 * 96; idx += 512) {
        int d = idx / 96, k = idx - d * 96;
        float v = W2[idx];
        unsigned short hb = f2bf(v);
        int ngf = d / 48, tt = (d % 48) / 16, r = d & 15;
        int ch = k >> 5, kl4 = (k & 31) >> 3, sb = k & 7;
        int fo = ((((ngf * 3 + tt) * 3 + ch) * 4 + kl4) * 16 + r) * 8 + sb;
        sBh[fo] = hb; sBl[fo] = f2bf(v - bf2f(hb));
    }
    if (tid < 96) sb1[tid] = b1[tid];
    float bias[3]; int dvv[3];
    #pragma unroll
    for (int t = 0; t < 3; ++t) { dvv[t] = (ng * 3 + t) * 16 + l15; bias[t] = b2[dvv[t]]; }

    for (int tile = blockIdx.x; tile < ntiles; tile += 512) {
        const int e0 = tile * 64;
        __syncthreads();
        for (int idx = tid; idx < 64 * 20; idx += 512) {
            int e = idx / 20, k = idx - e * 20;
            float v = 0.f;
            if (k < 17 && e0 + e < E) v = ea[(size_t)(e0 + e) * 17 + k];
            sea[e][k] = v;
        }
        if (tid < 64) {
            int e = e0 + tid;
            ssrc[tid] = (e < E) ? ei[e] : 0;
            sdst[tid] = (e < E) ? ei[E + e] : 0;
        }
        __syncthreads();
        {
            float hacc[4][3];
            #pragma unroll
            for (int i = 0; i < 4; ++i) { hacc[i][0]=sb1[c]; hacc[i][1]=sb1[c+32]; hacc[i][2]=sb1[c+64]; }
            #pragma unroll
            for (int k0 = 0; k0 < 20; k0 += 4) {
                float4 w0 = *(const float4*)&sW1f[c][k0];
                float4 w1 = *(const float4*)&sW1f[c + 32][k0];
                float4 w2 = *(const float4*)&sW1f[c + 64][k0];
                #pragma unroll
                for (int i = 0; i < 4; ++i) {
                    float4 av = *(const float4*)&sea[g * 4 + i][k0];
                    hacc[i][0] = fmaf(av.w, w0.w, fmaf(av.z, w0.z, fmaf(av.y, w0.y, fmaf(av.x, w0.x, hacc[i][0]))));
                    hacc[i][1] = fmaf(av.w, w1.w, fmaf(av.z, w1.z, fmaf(av.y, w1.y, fmaf(av.x, w1.x, hacc[i][1]))));
                    hacc[i][2] = fmaf(av.w, w2.w, fmaf(av.z, w2.z, fmaf(av.y, w2.y, fmaf(av.x, w2.x, hacc[i][2]))));
                }
            }
            #pragma unroll
            for (int i = 0; i < 4; ++i) {
                int e = g * 4 + i;
                #pragma unroll
                for (int j = 0; j < 3; ++j) {
                    float v = fmaxf(hacc[i][j], 0.f);
                    unsigned short hb = f2bf(v);
                    sAh2[j][e][c] = hb; sAl2[j][e][c] = f2bf(v - bf2f(hb));
                }
            }
        }
        __syncthreads();
        f32x4 acc[3];
        #pragma unroll
        for (int t = 0; t < 3; ++t) acc[t] = (f32x4){0.f, 0.f, 0.f, 0.f};
        const int arow = mr * 16 + l15;
        #pragma unroll
        for (int chunk = 0; chunk < 3; ++chunk) {
            s16x8 a_hi = *(const s16x8*)&sAh2[chunk][arow][l4 * 8];
            s16x8 a_lo = *(const s16x8*)&sAl2[chunk][arow][l4 * 8];
            #pragma unroll
            for (int t = 0; t < 3; ++t) {
                const int base = (((ng * 3 + t) * 3 + chunk) * 64 + lane) * 8;
                s16x8 b_hi = *(const s16x8*)&sBh[base];
                s16x8 b_lo = *(const s16x8*)&sBl[base];
                acc[t] = __builtin_amdgcn_mfma_f32_16x16x32_bf16(a_hi, b_hi, acc[t], 0, 0, 0);
                acc[t] = __builtin_amdgcn_mfma_f32_16x16x32_bf16(a_hi, b_lo, acc[t], 0, 0, 0);
                acc[t] = __builtin_amdgcn_mfma_f32_16x16x32_bf16(a_lo, b_hi, acc[t], 0, 0, 0);
            }
        }
        #pragma unroll
        for (int t = 0; t < 3; ++t)
            #pragma unroll
            for (int j = 0; j < 4; ++j) {
                int el = mr * 16 + l4 * 4 + j;
                int e  = e0 + el;
                if (e < E) {
                    int s = ssrc[el], dn = sdst[el];
                    atomicAdd(&agg[(size_t)dn * 96 + dvv[t]],
                              (acc[t][j] + bias[t]) * x[(size_t)s * 96 + dvv[t]]);
                }
            }
    }
}

// ---------------------------------------------------------------------------
// Node kernel: out = relu(x @ Ws^T + bs + agg @ Wn^T + bn); agg may alias out.
// ---------------------------------------------------------------------------
__global__ __launch_bounds__(NBLK, 4) void node_kernel(
    const float* __restrict__ x,
    const float* agg,
    const float* __restrict__ Ws, const float* __restrict__ bs,
    const float* __restrict__ Wn, const float* __restrict__ bn,
    float* out, int N)
{
    __shared__ float sW[96][100];
    __shared__ float sxa[TN][100];
    __shared__ float sbias[96];

    const int tid = threadIdx.x;
    const int c = tid & 31, g = tid >> 5;
    const int n0 = blockIdx.x * TN;

    if (tid < 96) sbias[tid] = bs[tid] + bn[tid];

    float acc[4][3];
    #pragma unroll
    for (int i = 0; i < 4; ++i)
        for (int j = 0; j < 3; ++j) acc[i][j] = 0.f;

    for (int ph = 0; ph < 2; ++ph) {
        const float* W   = ph ? Wn : Ws;
        const float* src = ph ? agg : x;
        __syncthreads();
        for (int idx = tid; idx < 96 * 24; idx += NBLK) {
            int d = idx / 24, kq = idx - d * 24;
            *(float4*)&sW[d][kq * 4] = *(const float4*)&W[d * 96 + kq * 4];
        }
        for (int idx = tid; idx < TN * 24; idx += NBLK) {
            int n = idx / 24, kq = idx - n * 24;
            float4 v = make_float4(0.f, 0.f, 0.f, 0.f);
            if (n0 + n < N) v = *(const float4*)&src[(size_t)(n0 + n) * 96 + kq * 4];
            *(float4*)&sxa[n][kq * 4] = v;
        }
        __syncthreads();
        #pragma unroll 2
        for (int k0 = 0; k0 < 96; k0 += 4) {
            float4 w0 = *(const float4*)&sW[c][k0];
            float4 w1 = *(const float4*)&sW[c + 32][k0];
            float4 w2 = *(const float4*)&sW[c + 64][k0];
            #pragma unroll
            for (int i = 0; i < 4; ++i) {
                float4 xv = *(const float4*)&sxa[g * 4 + i][k0];
                acc[i][0] = fmaf(xv.w, w0.w, fmaf(xv.z, w0.z, fmaf(xv.y, w0.y, fmaf(xv.x, w0.x, acc[i][0]))));
                acc[i][1] = fmaf(xv.w, w1.w, fmaf(xv.z, w1.z, fmaf(xv.y, w1.y, fmaf(xv.x, w1.x, acc[i][1]))));
                acc[i][2] = fmaf(xv.w, w2.w, fmaf(xv.z, w2.z, fmaf(xv.y, w2.y, fmaf(xv.x, w2.x, acc[i][2]))));
            }
        }
    }

    #pragma unroll
    for (int i = 0; i < 4; ++i) {
        int n = n0 + g * 4 + i;
        if (n < N) {
            out[(size_t)n * 96 + c]      = fmaxf(acc[i][0] + sbias[c], 0.f);
            out[(size_t)n * 96 + c + 32] = fmaxf(acc[i][1] + sbias[c + 32], 0.f);
            out[(size_t)n * 96 + c + 64] = fmaxf(acc[i][2] + sbias[c + 64], 0.f);
        }
    }
}

extern "C" void kernel_launch(void* const* d_in, const int* in_sizes, int n_in,
                              void* d_out, int out_size, void* d_ws, size_t ws_size,
                              hipStream_t stream) {
    const float* x  = (const float*)d_in[0];
    const int*   ei = (const int*)d_in[1];
    const float* ea = (const float*)d_in[2];
    const float* W1 = (const float*)d_in[3];
    const float* b1 = (const float*)d_in[4];
    const float* W2 = (const float*)d_in[5];
    const float* b2 = (const float*)d_in[6];
    const float* Ws = (const float*)d_in[7];
    const float* bs = (const float*)d_in[8];
    const float* Wn = (const float*)d_in[9];
    const float* bn = (const float*)d_in[10];
    float* out = (float*)d_out;

    const int N  = in_sizes[0] / 96;
    const int E  = in_sizes[2] / 17;
    const int nb = (N + NPB - 1) / NPB;

    // ws: pe_arr[E] (8B) | cntpad[LBK*16] | rs[nb+1]
    const size_t need = (size_t)E * 8 + ((size_t)LBK * 16 + nb + 1) * 4;

    if (ws_size >= need && nb <= LBK && nb <= 1024) {
        uint2* pe_arr = (uint2*)d_ws;
        int*   cntpad = (int*)(pe_arr + E);
        int*   rs     = cntpad + LBK * 16;

        hipMemsetAsync(cntpad, 0, (size_t)LBK * 16 * sizeof(int), stream);
        hist_bucket<<<256, 256, 0, stream>>>(ei, cntpad, E, nb);
        scan_bucket<<<1, 1024, 0, stream>>>(cntpad, rs, nb);
        scatter_bucket<<<(E + 255) / 256, 256, 0, stream>>>(ei, cntpad, pe_arr, E);
        // agg = out; edge_csr writes every row (no memset needed)
        edge_csr_kernel<<<nb, EBLK, 0, stream>>>(
            x, pe_arr, ea, W1, b1, W2, b2, rs, out, N, E);
    } else {
        hipMemsetAsync(out, 0, (size_t)N * 96 * sizeof(float), stream);
        edge_kernel_atomic<<<512, 512, 0, stream>>>(x, ei, ea, W1, b1, W2, b2, out, N, E);
    }
    node_kernel<<<(N + TN - 1) / TN, NBLK, 0, stream>>>(x, out, Ws, bs, Wn, bn, out, N);
}

// Round 12
// 348.664 us; speedup vs baseline: 2.4337x; 1.7748x over previous
//
#include <hip/hip_runtime.h>

#define EBLK 512      // edge kernel threads (8 waves)
#define NPB  26       // nodes owned per edge block
#define TEK  64       // edges per tile
#define SCAP 768      // in-LDS sorted key capacity (mean 416 + 17 sigma)
#define NBLK 512
#define TN   64
#define LBK  2048     // bucket-hist capacity (>= nb = ceil(N/NPB) = 1924)

typedef float f32x4 __attribute__((ext_vector_type(4)));
typedef short s16x8 __attribute__((ext_vector_type(8)));
typedef unsigned long long u64;

static __device__ __forceinline__ unsigned short f2bf(float f) {
    unsigned int u = __float_as_uint(f);
    u += 0x7FFFu + ((u >> 16) & 1u);          // round-to-nearest-even
    return (unsigned short)(u >> 16);
}
static __device__ __forceinline__ float bf2f(unsigned short s) {
    return __uint_as_float(((unsigned int)s) << 16);
}
static __device__ __forceinline__ u64 pack4(unsigned short a, unsigned short b,
                                            unsigned short c, unsigned short d) {
    return (u64)a | ((u64)b << 16) | ((u64)c << 32) | ((u64)d << 48);
}

// LDS-visibility barrier WITHOUT vmcnt drain (no "memory" clobber).
static __device__ __forceinline__ void bar_sync() {
    __builtin_amdgcn_sched_barrier(0);
    asm volatile("s_waitcnt lgkmcnt(0)");
    __builtin_amdgcn_s_barrier();
    __builtin_amdgcn_sched_barrier(0);
}

// ---------------------------------------------------------------------------
// Bucket sort by dst/NPB (coarse). cntpad stride-16 (one counter / 64B line).
// ---------------------------------------------------------------------------
__global__ __launch_bounds__(256) void hist_bucket(const int* __restrict__ ei,
                                                   int* __restrict__ cntpad, int E, int nb) {
    __shared__ int lh[LBK];
    for (int i = threadIdx.x; i < LBK; i += 256) lh[i] = 0;
    __syncthreads();
    for (int e = blockIdx.x * 256 + threadIdx.x; e < E; e += gridDim.x * 256)
        atomicAdd(&lh[ei[E + e] / NPB], 1);
    __syncthreads();
    for (int i = threadIdx.x; i < nb; i += 256)
        if (lh[i]) atomicAdd(&cntpad[i * 16], lh[i]);
}

__global__ __launch_bounds__(1024) void scan_bucket(int* __restrict__ cntpad,
                                                    int* __restrict__ rs, int nb) {
    __shared__ int s[1024];
    const int t = threadIdx.x;
    const int chunk = (nb + 1023) >> 10;
    const int b0 = t * chunk;
    const int b1 = min(b0 + chunk, nb);
    int local = 0;
    for (int i = b0; i < b1; ++i) local += cntpad[i * 16];
    s[t] = local;
    __syncthreads();
    for (int off = 1; off < 1024; off <<= 1) {
        int u = (t >= off) ? s[t - off] : 0;
        __syncthreads();
        s[t] += u;
        __syncthreads();
    }
    int run = s[t] - local;
    for (int i = b0; i < b1; ++i) {
        int c = cntpad[i * 16];
        rs[i] = run; cntpad[i * 16] = run;
        run += c;
    }
    if (t == 1023) rs[nb] = run;
}

__global__ __launch_bounds__(256) void scatter_bucket(const int* __restrict__ ei,
                                                      int* __restrict__ cntpad,
                                                      uint2* __restrict__ pe_arr, int E) {
    int e = blockIdx.x * 256 + threadIdx.x;
    if (e < E) {
        int d = ei[E + e], s0 = ei[e];
        int pos = atomicAdd(&cntpad[(d / NPB) * 16], 1);
        pe_arr[pos] = make_uint2(((unsigned)d << 16) | (unsigned)s0, (unsigned)e);
    }
}

// swizzled byte offsets: 64B rows, XOR 16B chunk by (edge&3)
#define SEA_BYTE(edge, kbyte) ((((edge) * 64) + (kbyte)) ^ (((edge)&3) << 4))
#define SA_BYTE(ch, edge, kbyte) (((((ch)*TEK + (edge)) * 64) + (kbyte)) ^ (((edge)&3) << 4))

// ---------------------------------------------------------------------------
// Edge kernel: block owns nodes [b*NPB,(b+1)*NPB). Bucket keys sorted IN-LDS
// at block start (restores dst-runs -> register merge kills LDS atomics).
//  A: keys(t) from skeys | x gathers | ea prefetch(t+1) | GEMM1 (MFMA)
//  BAR(lgkm) | B: GEMM2 (MFMA) | stage sea(t+1) | merge -> few ds_add | BAR
// LDS ~78KB -> 2 blocks/CU. Zero global atomics; flush = plain stores.
// GEMM1 split-3 (W1 hi/lo x ea hi/lo); GEMM2: (h_hi + h_lo) x W2_hi.
// ---------------------------------------------------------------------------
__global__ __launch_bounds__(EBLK) void edge_csr_kernel(
    const float* __restrict__ x,          // [N][96]
    const uint2* __restrict__ pe_arr,     // [E] (dst<<16|src, eid), bucket-sorted
    const float* __restrict__ ea,         // [E][17] original order
    const float* __restrict__ W1, const float* __restrict__ b1,
    const float* __restrict__ W2, const float* __restrict__ b2,
    const int* __restrict__ rs,           // [nb+1] bucket starts
    float* agg, int N, int E)
{
    __shared__ unsigned short sBh[9216];              // W2 hi, fragment-linear
    __shared__ unsigned short sW1h[3072], sW1l[3072]; // W1 hi/lo fragment-linear (K=32)
    __shared__ unsigned short seaH[TEK * 32], seaL[TEK * 32]; // ea bf16 hi/lo, swizzled
    __shared__ unsigned short sAh[3 * TEK * 32];      // h hi, swizzled
    __shared__ unsigned short sAl[3 * TEK * 32];      // h lo
    __shared__ float accum[NPB][96];
    __shared__ uint2 skeys[SCAP];
    __shared__ int   scnt[NPB + 2];

    const int tid  = threadIdx.x;
    const int lane = tid & 63;
    const int wv8  = tid >> 6;             // wave 0..7
    const int mr   = wv8 & 3;              // GEMM2 edge-group of 16
    const int ng   = wv8 >> 2;             // GEMM2 dv half
    const int l15  = lane & 15;
    const int l4   = lane >> 4;
    const int nt   = wv8 & 3;              // GEMM1 edge tile (16)
    const int mgrp = (wv8 >> 2) * 3;       // GEMM1 dv tile group
    const int eb   = nt * 16 + l15;        // GEMM1 edge column
    const int pe   = tid >> 3, ps = tid & 7; // ea prefetch: edge, quarter

    const int nb0    = blockIdx.x * NPB;
    const int ebeg   = rs[blockIdx.x];
    const int ecount = rs[blockIdx.x + 1] - ebeg;
    const int ntiles = (ecount + TEK - 1) / TEK;

    // ---- in-LDS counting sort of bucket keys by dloc ----
    if (tid < NPB + 2) scnt[tid] = 0;
    __syncthreads();
    const int ec2 = min(ecount, SCAP);
    uint2 k0, k1; int d0 = -1, d1 = -1;
    if (tid < ec2)       { k0 = pe_arr[ebeg + tid];       d0 = (int)(k0.x >> 16) - nb0; }
    if (512 + tid < ec2) { k1 = pe_arr[ebeg + 512 + tid]; d1 = (int)(k1.x >> 16) - nb0; }
    if (d0 >= 0) atomicAdd(&scnt[d0], 1);
    if (d1 >= 0) atomicAdd(&scnt[d1], 1);
    __syncthreads();
    if (tid == 0) {
        int run = 0;
        for (int m = 0; m < NPB; ++m) { int c = scnt[m]; scnt[m] = run; run += c; }
    }
    __syncthreads();
    if (d0 >= 0) skeys[atomicAdd(&scnt[d0], 1)] = k0;
    if (d1 >= 0) skeys[atomicAdd(&scnt[d1], 1)] = k1;
    __syncthreads();

    // ---- tile0 ea prefetch (uses skeys; flies under W staging) ----
    float pf[4];
    {
        int idx = pe;
        int eid = 0;
        bool val = idx < ecount;
        if (val) eid = (idx < SCAP) ? (int)skeys[idx].y : (int)pe_arr[ebeg + idx].y;
        const float* er = ea + (size_t)eid * 17;
        #pragma unroll
        for (int u = 0; u < 4; ++u) {
            int k = ps * 4 + u;
            pf[u] = (val && k < 17) ? er[k] : 0.f;
        }
    }

    // ---- one-time staging ----
    for (int idx = tid; idx < 96 * 96; idx += EBLK) {
        int d = idx / 96, k = idx - d * 96;
        int ngf = d / 48, tt = (d % 48) / 16, r = d & 15;
        int ch = k >> 5, kl4 = (k & 31) >> 3, sb = k & 7;
        int fo = ((((ngf * 3 + tt) * 3 + ch) * 4 + kl4) * 16 + r) * 8 + sb;
        sBh[fo] = f2bf(W2[idx]);
    }
    for (int idx = tid; idx < 96 * 32; idx += EBLK) {
        int d = idx >> 5, k = idx & 31;
        float v = (k < 17) ? W1[d * 17 + k] : 0.f;
        unsigned short hb = f2bf(v);
        int mt = d >> 4, r = d & 15;
        int fo = ((mt * 4 + (k >> 3)) * 16 + r) * 8 + (k & 7);
        sW1h[fo] = hb;
        sW1l[fo] = f2bf(v - bf2f(hb));
    }
    for (int idx = tid; idx < NPB * 96; idx += EBLK) (&accum[0][0])[idx] = 0.f;

    float b1v[3][4];
    #pragma unroll
    for (int i = 0; i < 3; ++i)
        #pragma unroll
        for (int j = 0; j < 4; ++j)
            b1v[i][j] = b1[(mgrp + i) * 16 + l4 * 4 + j];

    float bias[3]; int dv[3];
    #pragma unroll
    for (int t = 0; t < 3; ++t) {
        dv[t]   = (ng * 3 + t) * 16 + l15;
        bias[t] = b2[dv[t]];
    }

    __syncthreads();   // staging done; tile0 pf drained
    {   // stage tile0 ea
        unsigned short hh[4], ll[4];
        #pragma unroll
        for (int u = 0; u < 4; ++u) {
            hh[u] = f2bf(pf[u]);
            ll[u] = f2bf(pf[u] - bf2f(hh[u]));
        }
        *(u64*)((char*)seaH + SEA_BYTE(pe, ps * 8)) = pack4(hh[0], hh[1], hh[2], hh[3]);
        *(u64*)((char*)seaL + SEA_BYTE(pe, ps * 8)) = pack4(ll[0], ll[1], ll[2], ll[3]);
    }
    __syncthreads();

    for (int t = 0; t < ntiles; ++t) {
        const bool nxt = (t + 1) < ntiles;
        const int toff = t * TEK;
        const bool fromLds = (toff < SCAP);

        // ===== Phase A =====
        // keys for this wave's 4 edges
        const int g16 = mr * 16;
        int sg[4], dl[4];
        #pragma unroll
        for (int j = 0; j < 4; ++j) {
            int idx = toff + g16 + l4 * 4 + j;
            bool val = idx < ecount;
            uint2 K = fromLds ? skeys[min(idx, SCAP - 1)]
                              : (val ? pe_arr[ebeg + idx] : make_uint2(0u, 0u));
            dl[j] = val ? (int)(K.x >> 16) - nb0 : -1;
            sg[j] = val ? (int)(K.x & 0xFFFFu) : 0;
        }

        // x gathers (oldest VMEM this iteration)
        float xg[12];
        #pragma unroll
        for (int t3 = 0; t3 < 3; ++t3)
            #pragma unroll
            for (int j = 0; j < 4; ++j)
                xg[t3 * 4 + j] = x[(size_t)sg[j] * 96 + dv[t3]];

        // ea prefetch for tile t+1
        if (nxt) {
            int idx = toff + TEK + pe;
            int eid = 0;
            bool val = idx < ecount;
            if (val) eid = (idx < SCAP) ? (int)skeys[idx].y : (int)pe_arr[ebeg + idx].y;
            const float* er = ea + (size_t)eid * 17;
            #pragma unroll
            for (int u = 0; u < 4; ++u) {
                int k = ps * 4 + u;
                pf[u] = (val && k < 17) ? er[k] : 0.f;
            }
        }

        // GEMM1: h = relu(ea @ W1^T + b1)  (split-3, A=W1 -> D rows are dv)
        {
            s16x8 bh = *(const s16x8*)((const char*)seaH + SEA_BYTE(eb, l4 * 16));
            s16x8 bl = *(const s16x8*)((const char*)seaL + SEA_BYTE(eb, l4 * 16));
            #pragma unroll
            for (int i = 0; i < 3; ++i) {
                const int mt = mgrp + i;
                s16x8 ah = *(const s16x8*)&sW1h[((mt * 4 + l4) * 16 + l15) * 8];
                s16x8 al = *(const s16x8*)&sW1l[((mt * 4 + l4) * 16 + l15) * 8];
                f32x4 dd = (f32x4){0.f, 0.f, 0.f, 0.f};
                dd = __builtin_amdgcn_mfma_f32_16x16x32_bf16(ah, bh, dd, 0, 0, 0);
                dd = __builtin_amdgcn_mfma_f32_16x16x32_bf16(al, bh, dd, 0, 0, 0);
                dd = __builtin_amdgcn_mfma_f32_16x16x32_bf16(ah, bl, dd, 0, 0, 0);
                unsigned short hh[4], hl[4];
                #pragma unroll
                for (int j = 0; j < 4; ++j) {
                    float hv = fmaxf(dd[j] + b1v[i][j], 0.f);
                    hh[j] = f2bf(hv);
                    hl[j] = f2bf(hv - bf2f(hh[j]));
                }
                const int db = mt * 16 + l4 * 4;
                const int by = SA_BYTE(db >> 5, eb, (db & 31) * 2);
                *(u64*)((char*)sAh + by) = pack4(hh[0], hh[1], hh[2], hh[3]);
                *(u64*)((char*)sAl + by) = pack4(hl[0], hl[1], hl[2], hl[3]);
            }
        }
        bar_sync();   // BAR1: sA visible; VMEM rides

        // ===== Phase B =====
        // GEMM2: w = h @ W2_hi^T  (h hi+lo)
        f32x4 acc[3];
        #pragma unroll
        for (int t3 = 0; t3 < 3; ++t3) acc[t3] = (f32x4){0.f, 0.f, 0.f, 0.f};
        const int arow = mr * 16 + l15;
        #pragma unroll
        for (int chunk = 0; chunk < 3; ++chunk) {
            s16x8 a_hi = *(const s16x8*)((const char*)sAh + SA_BYTE(chunk, arow, l4 * 16));
            s16x8 a_lo = *(const s16x8*)((const char*)sAl + SA_BYTE(chunk, arow, l4 * 16));
            #pragma unroll
            for (int t3 = 0; t3 < 3; ++t3) {
                const int base = (((ng * 3 + t3) * 3 + chunk) * 64 + lane) * 8;
                s16x8 b_hi = *(const s16x8*)&sBh[base];
                acc[t3] = __builtin_amdgcn_mfma_f32_16x16x32_bf16(a_hi, b_hi, acc[t3], 0, 0, 0);
                acc[t3] = __builtin_amdgcn_mfma_f32_16x16x32_bf16(a_lo, b_hi, acc[t3], 0, 0, 0);
            }
        }

        // stage sea(t+1) from pf (counted vmcnt: waits pf, drains gathers under GEMMs)
        if (nxt) {
            unsigned short hh[4], ll[4];
            #pragma unroll
            for (int u = 0; u < 4; ++u) {
                hh[u] = f2bf(pf[u]);
                ll[u] = f2bf(pf[u] - bf2f(hh[u]));
            }
            *(u64*)((char*)seaH + SEA_BYTE(pe, ps * 8)) = pack4(hh[0], hh[1], hh[2], hh[3]);
            *(u64*)((char*)seaL + SEA_BYTE(pe, ps * 8)) = pack4(ll[0], ll[1], ll[2], ll[3]);
        }

        // messages + register segmented merge -> few LDS atomics
        float v[3][4];
        #pragma unroll
        for (int t3 = 0; t3 < 3; ++t3)
            #pragma unroll
            for (int j = 0; j < 4; ++j)
                v[t3][j] = (acc[t3][j] + bias[t3]) * xg[t3 * 4 + j];

        int dFirst = __shfl(dl[0], 0, 64);
        bool myuni = (dl[0] == dFirst) & (dl[1] == dFirst) &
                     (dl[2] == dFirst) & (dl[3] == dFirst);
        if (__all(myuni) && dFirst >= 0) {
            #pragma unroll
            for (int t3 = 0; t3 < 3; ++t3) {
                float s4 = (v[t3][0] + v[t3][1]) + (v[t3][2] + v[t3][3]);
                s4 += __shfl_xor(s4, 16, 64);
                s4 += __shfl_xor(s4, 32, 64);
                if (l4 == 0)
                    atomicAdd(&accum[dFirst][dv[t3]], s4);
            }
        } else {
            #pragma unroll
            for (int t3 = 0; t3 < 3; ++t3) {
                float a = v[t3][0]; int cd = dl[0];
                #pragma unroll
                for (int j = 1; j < 4; ++j) {
                    if (dl[j] == cd) a += v[t3][j];
                    else {
                        if (cd >= 0) atomicAdd(&accum[cd][dv[t3]], a);
                        a = v[t3][j]; cd = dl[j];
                    }
                }
                if (cd >= 0) atomicAdd(&accum[cd][dv[t3]], a);
            }
        }

        bar_sync();   // BAR2
    }

    __syncthreads();
    // flush owned node range: plain coalesced stores, full coverage
    for (int idx = tid; idx < NPB * 96; idx += EBLK) {
        int n = nb0 + idx / 96;
        if (n < N) agg[(size_t)n * 96 + (idx % 96)] = (&accum[0][0])[idx];
    }
}

// ---------------------------------------------------------------------------
// Fallback edge kernel (proven r4 atomic version): used only if ws too small.
// ---------------------------------------------------------------------------
__global__ __launch_bounds__(512, 4) void edge_kernel_atomic(
    const float* __restrict__ x, const int* __restrict__ ei,
    const float* __restrict__ ea, const float* __restrict__ W1,
    const float* __restrict__ b1, const float* __restrict__ W2,
    const float* __restrict__ b2, float* __restrict__ agg, int N, int E)
{
    __shared__ unsigned short sBh2[9216], sBl2[9216];
    __shared__ unsigned short sAh2[3][64][40], sAl2[3][64][40];
    __shared__ float sW1f[96][20];
    __shared__ float sea[64][20];
    __shared__ float sb1[96];
    __shared__ int   ssrc[64], sdst[64];

    const int tid = threadIdx.x;
    const int c = tid & 31, g = tid >> 5;
    const int lane = tid & 63, wv = tid >> 6;
    const int mr = wv & 3, ng = wv >> 2;
    const int l15 = lane & 15, l4 = lane >> 4;
    const int ntiles = (E + 63) / 64;

    for (int idx = tid; idx < 96 * 20; idx += 512) {
        int d = idx / 20, k = idx - d * 20;
        sW1f[d][k] = (k < 17) ? W1[d * 17 + k] : 0.f;
    }
    for (int idx = tid; idx < 96 * 96; idx += 512) {
        int d = idx / 96, k = idx - d * 96;
        float v = W2[idx];
        unsigned short hb = f2bf(v);
        int ngf = d / 48, tt = (d % 48) / 16, r = d & 15;
        int ch = k >> 5, kl4 = (k & 31) >> 3, sb = k & 7;
        int fo = ((((ngf * 3 + tt) * 3 + ch) * 4 + kl4) * 16 + r) * 8 + sb;
        sBh2[fo] = hb; sBl2[fo] = f2bf(v - bf2f(hb));
    }
    if (tid < 96) sb1[tid] = b1[tid];
    float bias[3]; int dvv[3];
    #pragma unroll
    for (int t = 0; t < 3; ++t) { dvv[t] = (ng * 3 + t) * 16 + l15; bias[t] = b2[dvv[t]]; }

    for (int tile = blockIdx.x; tile < ntiles; tile += 512) {
        const int e0 = tile * 64;
        __syncthreads();
        for (int idx = tid; idx < 64 * 20; idx += 512) {
            int e = idx / 20, k = idx - e * 20;
            float v = 0.f;
            if (k < 17 && e0 + e < E) v = ea[(size_t)(e0 + e) * 17 + k];
            sea[e][k] = v;
        }
        if (tid < 64) {
            int e = e0 + tid;
            ssrc[tid] = (e < E) ? ei[e] : 0;
            sdst[tid] = (e < E) ? ei[E + e] : 0;
        }
        __syncthreads();
        {
            float hacc[4][3];
            #pragma unroll
            for (int i = 0; i < 4; ++i) { hacc[i][0]=sb1[c]; hacc[i][1]=sb1[c+32]; hacc[i][2]=sb1[c+64]; }
            #pragma unroll
            for (int k0 = 0; k0 < 20; k0 += 4) {
                float4 w0 = *(const float4*)&sW1f[c][k0];
                float4 w1 = *(const float4*)&sW1f[c + 32][k0];
                float4 w2 = *(const float4*)&sW1f[c + 64][k0];
                #pragma unroll
                for (int i = 0; i < 4; ++i) {
                    float4 av = *(const float4*)&sea[g * 4 + i][k0];
                    hacc[i][0] = fmaf(av.w, w0.w, fmaf(av.z, w0.z, fmaf(av.y, w0.y, fmaf(av.x, w0.x, hacc[i][0]))));
                    hacc[i][1] = fmaf(av.w, w1.w, fmaf(av.z, w1.z, fmaf(av.y, w1.y, fmaf(av.x, w1.x, hacc[i][1]))));
                    hacc[i][2] = fmaf(av.w, w2.w, fmaf(av.z, w2.z, fmaf(av.y, w2.y, fmaf(av.x, w2.x, hacc[i][2]))));
                }
            }
            #pragma unroll
            for (int i = 0; i < 4; ++i) {
                int e = g * 4 + i;
                #pragma unroll
                for (int j = 0; j < 3; ++j) {
                    float v = fmaxf(hacc[i][j], 0.f);
                    unsigned short hb = f2bf(v);
                    sAh2[j][e][c] = hb; sAl2[j][e][c] = f2bf(v - bf2f(hb));
                }
            }
        }
        __syncthreads();
        f32x4 acc[3];
        #pragma unroll
        for (int t = 0; t < 3; ++t) acc[t] = (f32x4){0.f, 0.f, 0.f, 0.f};
        const int arow = mr * 16 + l15;
        #pragma unroll
        for (int chunk = 0; chunk < 3; ++chunk) {
            s16x8 a_hi = *(const s16x8*)&sAh2[chunk][arow][l4 * 8];
            s16x8 a_lo = *(const s16x8*)&sAl2[chunk][arow][l4 * 8];
            #pragma unroll
            for (int t = 0; t < 3; ++t) {
                const int base = (((ng * 3 + t) * 3 + chunk) * 64 + lane) * 8;
                s16x8 b_hi = *(const s16x8*)&sBh2[base];
                s16x8 b_lo = *(const s16x8*)&sBl2[base];
                acc[t] = __builtin_amdgcn_mfma_f32_16x16x32_bf16(a_hi, b_hi, acc[t], 0, 0, 0);
                acc[t] = __builtin_amdgcn_mfma_f32_16x16x32_bf16(a_hi, b_lo, acc[t], 0, 0, 0);
                acc[t] = __builtin_amdgcn_mfma_f32_16x16x32_bf16(a_lo, b_hi, acc[t], 0, 0, 0);
            }
        }
        #pragma unroll
        for (int t = 0; t < 3; ++t)
            #pragma unroll
            for (int j = 0; j < 4; ++j) {
                int el = mr * 16 + l4 * 4 + j;
                int e  = e0 + el;
                if (e < E) {
                    int s = ssrc[el], dn = sdst[el];
                    atomicAdd(&agg[(size_t)dn * 96 + dvv[t]],
                              (acc[t][j] + bias[t]) * x[(size_t)s * 96 + dvv[t]]);
                }
            }
    }
}

// ---------------------------------------------------------------------------
// Node kernel: out = relu(x @ Ws^T + bs + agg @ Wn^T + bn); agg may alias out.
// ---------------------------------------------------------------------------
__global__ __launch_bounds__(NBLK, 4) void node_kernel(
    const float* __restrict__ x,
    const float* agg,
    const float* __restrict__ Ws, const float* __restrict__ bs,
    const float* __restrict__ Wn, const float* __restrict__ bn,
    float* out, int N)
{
    __shared__ float sW[96][100];
    __shared__ float sxa[TN][100];
    __shared__ float sbias[96];

    const int tid = threadIdx.x;
    const int c = tid & 31, g = tid >> 5;
    const int n0 = blockIdx.x * TN;

    if (tid < 96) sbias[tid] = bs[tid] + bn[tid];

    float acc[4][3];
    #pragma unroll
    for (int i = 0; i < 4; ++i)
        for (int j = 0; j < 3; ++j) acc[i][j] = 0.f;

    for (int ph = 0; ph < 2; ++ph) {
        const float* W   = ph ? Wn : Ws;
        const float* src = ph ? agg : x;
        __syncthreads();
        for (int idx = tid; idx < 96 * 24; idx += NBLK) {
            int d = idx / 24, kq = idx - d * 24;
            *(float4*)&sW[d][kq * 4] = *(const float4*)&W[d * 96 + kq * 4];
        }
        for (int idx = tid; idx < TN * 24; idx += NBLK) {
            int n = idx / 24, kq = idx - n * 24;
            float4 v = make_float4(0.f, 0.f, 0.f, 0.f);
            if (n0 + n < N) v = *(const float4*)&src[(size_t)(n0 + n) * 96 + kq * 4];
            *(float4*)&sxa[n][kq * 4] = v;
        }
        __syncthreads();
        #pragma unroll 2
        for (int k0 = 0; k0 < 96; k0 += 4) {
            float4 w0 = *(const float4*)&sW[c][k0];
            float4 w1 = *(const float4*)&sW[c + 32][k0];
            float4 w2 = *(const float4*)&sW[c + 64][k0];
            #pragma unroll
            for (int i = 0; i < 4; ++i) {
                float4 xv = *(const float4*)&sxa[g * 4 + i][k0];
                acc[i][0] = fmaf(xv.w, w0.w, fmaf(xv.z, w0.z, fmaf(xv.y, w0.y, fmaf(xv.x, w0.x, acc[i][0]))));
                acc[i][1] = fmaf(xv.w, w1.w, fmaf(xv.z, w1.z, fmaf(xv.y, w1.y, fmaf(xv.x, w1.x, acc[i][1]))));
                acc[i][2] = fmaf(xv.w, w2.w, fmaf(xv.z, w2.z, fmaf(xv.y, w2.y, fmaf(xv.x, w2.x, acc[i][2]))));
            }
        }
    }

    #pragma unroll
    for (int i = 0; i < 4; ++i) {
        int n = n0 + g * 4 + i;
        if (n < N) {
            out[(size_t)n * 96 + c]      = fmaxf(acc[i][0] + sbias[c], 0.f);
            out[(size_t)n * 96 + c + 32] = fmaxf(acc[i][1] + sbias[c + 32], 0.f);
            out[(size_t)n * 96 + c + 64] = fmaxf(acc[i][2] + sbias[c + 64], 0.f);
        }
    }
}

extern "C" void kernel_launch(void* const* d_in, const int* in_sizes, int n_in,
                              void* d_out, int out_size, void* d_ws, size_t ws_size,
                              hipStream_t stream) {
    const float* x  = (const float*)d_in[0];
    const int*   ei = (const int*)d_in[1];
    const float* ea = (const float*)d_in[2];
    const float* W1 = (const float*)d_in[3];
    const float* b1 = (const float*)d_in[4];
    const float* W2 = (const float*)d_in[5];
    const float* b2 = (const float*)d_in[6];
    const float* Ws = (const float*)d_in[7];
    const float* bs = (const float*)d_in[8];
    const float* Wn = (const float*)d_in[9];
    const float* bn = (const float*)d_in[10];
    float* out = (float*)d_out;

    const int N  = in_sizes[0] / 96;
    const int E  = in_sizes[2] / 17;
    const int nb = (N + NPB - 1) / NPB;

    // ws: pe_arr[E] (8B) | cntpad[LBK*16] | rs[nb+1]
    const size_t need = (size_t)E * 8 + ((size_t)LBK * 16 + nb + 1) * 4;

    if (ws_size >= need && nb <= LBK) {
        uint2* pe_arr = (uint2*)d_ws;
        int*   cntpad = (int*)(pe_arr + E);
        int*   rs     = cntpad + LBK * 16;

        hipMemsetAsync(cntpad, 0, (size_t)LBK * 16 * sizeof(int), stream);
        hist_bucket<<<256, 256, 0, stream>>>(ei, cntpad, E, nb);
        scan_bucket<<<1, 1024, 0, stream>>>(cntpad, rs, nb);
        scatter_bucket<<<(E + 255) / 256, 256, 0, stream>>>(ei, cntpad, pe_arr, E);
        // agg = out; edge_csr writes every row (no memset needed)
        edge_csr_kernel<<<nb, EBLK, 0, stream>>>(
            x, pe_arr, ea, W1, b1, W2, b2, rs, out, N, E);
    } else {
        hipMemsetAsync(out, 0, (size_t)N * 96 * sizeof(float), stream);
        edge_kernel_atomic<<<512, 512, 0, stream>>>(x, ei, ea, W1, b1, W2, b2, out, N, E);
    }
    node_kernel<<<(N + TN - 1) / TN, NBLK, 0, stream>>>(x, out, Ws, bs, Wn, bn, out, N);
}